// Round 3
// baseline (638.591 us; speedup 1.0000x reference)
//
#include <hip/hip_runtime.h>
#include <cstdint>
#include <cstddef>

// Problem constants: B=32, LQ=LA=1024, H=512
#define NB   32
#define LQA  1024
#define HD   512

typedef __attribute__((ext_vector_type(4))) float  f32x4;
typedef __attribute__((ext_vector_type(8))) short  s16x8;   // 8 bf16 MFMA frag
typedef __attribute__((ext_vector_type(4))) unsigned short u16x4;
typedef __attribute__((ext_vector_type(2))) unsigned short u16x2;

static __device__ __forceinline__ unsigned short f2bf(float f) {
  unsigned int u = __builtin_bit_cast(unsigned int, f);
  u += 0x7fffu + ((u >> 16) & 1u);      // RNE
  return (unsigned short)(u >> 16);
}
static __device__ __forceinline__ u16x4 cvt4(f32x4 v) {
  u16x4 r;
  r.x = f2bf(v.x); r.y = f2bf(v.y); r.z = f2bf(v.z); r.w = f2bf(v.w);
  return r;
}

typedef __attribute__((address_space(1))) const void gas_void;
typedef __attribute__((address_space(3))) void las_void;
static __device__ __forceinline__ void gload_lds16(const void* g, void* l) {
  __builtin_amdgcn_global_load_lds((gas_void*)g, (las_void*)l, 16, 0, 0);
}

// ---------------------------------------------------------------------------
// K0 (merged q+a): per-batch 64x64 tile:
//   (a) fp32 copy -> concat-output left half
//   (b) bf16 row-major copy [LQA x HD]
//   (c) bf16 transposed copy [HD x LQA] (LDS pre-transposed write, vector read)
//   (d) atomic column sums  colsum[b][h] += sum_q src[b,q,h]  (fp32)
// grid: (8, 16, 2*NB), block 256.  z<NB -> q, else a.
// ---------------------------------------------------------------------------
__global__ __launch_bounds__(256) void k_prep(
    const float* __restrict__ qsrc, const float* __restrict__ asrc,
    float* __restrict__ out0, float* __restrict__ out1,
    unsigned short* __restrict__ qT, unsigned short* __restrict__ aT,
    unsigned short* __restrict__ qb16, unsigned short* __restrict__ ab16,
    float* __restrict__ qsum, float* __restrict__ asum)
{
  const int which = blockIdx.z >> 5;          // 0 = q, 1 = a
  const int b  = blockIdx.z & 31;
  const int h0 = blockIdx.x * 64;
  const int q0 = blockIdx.y * 64;
  const int t  = threadIdx.x;
  const int lane = t & 63;

  const float* src = which ? asrc : qsrc;
  float* out_left  = which ? out1 : out0;
  unsigned short* dstT = which ? aT : qT;
  unsigned short* dstN = which ? ab16 : qb16;
  float* sums          = which ? asum : qsum;

  __shared__ unsigned short T[64 * 66];   // [h-local][q-local], stride 66

  const float* sb = src + (size_t)b * LQA * HD;
  float* ob       = out_left + (size_t)b * LQA * 1024;
  unsigned short* db  = dstT + (size_t)b * HD * LQA;
  unsigned short* dbn = dstN + (size_t)b * LQA * HD;

  const int c = (t & 15) * 4;        // h-local col base (fixed across j)
  f32x4 csum = (f32x4)0.f;

#pragma unroll
  for (int j = 0; j < 4; ++j) {
    int r = (t >> 4) + 16 * j;       // q-local row
    f32x4 v = *(const f32x4*)(sb + (size_t)(q0 + r) * HD + h0 + c);
    *(f32x4*)(ob + (size_t)(q0 + r) * 1024 + h0 + c) = v;
    u16x4 cv = cvt4(v);
    *(u16x4*)&dbn[(size_t)(q0 + r) * HD + h0 + c] = cv;
    // pre-transposed scalar LDS writes: T[h][q]
    T[(c + 0) * 66 + r] = cv.x;
    T[(c + 1) * 66 + r] = cv.y;
    T[(c + 2) * 66 + r] = cv.z;
    T[(c + 3) * 66 + r] = cv.w;
    csum += v;
  }
  // column sums: reduce lanes sharing c (lane ^16, ^32), then atomics
#pragma unroll
  for (int k = 16; k <= 32; k <<= 1) {
    csum.x += __shfl_xor(csum.x, k);
    csum.y += __shfl_xor(csum.y, k);
    csum.z += __shfl_xor(csum.z, k);
    csum.w += __shfl_xor(csum.w, k);
  }
  if ((lane >> 4) == 0) {
    float* sp = sums + b * HD + h0 + c;
    atomicAdd(sp + 0, csum.x);
    atomicAdd(sp + 1, csum.y);
    atomicAdd(sp + 2, csum.z);
    atomicAdd(sp + 3, csum.w);
  }
  __syncthreads();
  // vectorized row reads of T -> global transposed store
#pragma unroll
  for (int j = 0; j < 4; ++j) {
    int f = t + 256 * j;
    int orow = f >> 4;               // h-local
    int cq = (f & 15) * 4;           // q-local
    u16x2 lo = *(const u16x2*)&T[orow * 66 + cq];
    u16x2 hi = *(const u16x2*)&T[orow * 66 + cq + 2];
    u16x4 v; v.x = lo.x; v.y = lo.y; v.z = hi.x; v.w = hi.y;
    *(u16x4*)&db[(size_t)(h0 + orow) * LQA + q0 + cq] = v;
  }
}

// ---------------------------------------------------------------------------
// K1: scores. E[b,q,a] = qm*am*exp(temp*dot(q,a)); writes E, ET (bf16) and
// atomic fp32 row sums (sumEq over a) and col sums (sumEa over q).
// 128x128 tile, BK=32, global_load_lds(16B). grid: (8,8,NB), block 256.
// ---------------------------------------------------------------------------
__global__ __launch_bounds__(256) void k_scores(
    const unsigned short* __restrict__ qb16, const unsigned short* __restrict__ ab16,
    const int* __restrict__ qmask, const int* __restrict__ amask,
    const float* __restrict__ temp_p,
    unsigned short* __restrict__ E, unsigned short* __restrict__ ET,
    float* __restrict__ sumEq, float* __restrict__ sumEa)
{
  const int b  = blockIdx.z;
  const int m0 = blockIdx.x * 128;
  const int n0 = blockIdx.y * 128;
  const int t  = threadIdx.x;
  const int lane = t & 63;
  const int w  = t >> 6;
  const int moff = (w & 1) * 64;
  const int noff = (w >> 1) * 64;
  const int lrow = lane & 15;
  const int quad = lane >> 4;

  // main loop: As[128][32], Bs[128][32] (8 KB each)
  // epilogue: Cs_h[128][68] (17408 B) + CsT_h[64][132] (16896 B)
  __shared__ __align__(16) unsigned short smem[8704 + 8448];
  unsigned short* As = smem;
  unsigned short* Bs = smem + 4096;
  unsigned short* Cs_h  = smem;          // [128][68]
  unsigned short* CsT_h = smem + 8704;   // [64][132]

  const unsigned short* qb = qb16 + (size_t)b * LQA * HD;
  const unsigned short* ab = ab16 + (size_t)b * LQA * HD;

  const int fa = t, fb = t + 256;
  const unsigned short* qg0 = qb + (size_t)(m0 + (fa >> 2)) * HD + (fa & 3) * 8;
  const unsigned short* qg1 = qb + (size_t)(m0 + (fb >> 2)) * HD + (fb & 3) * 8;
  const unsigned short* ag0 = ab + (size_t)(n0 + (fa >> 2)) * HD + (fa & 3) * 8;
  const unsigned short* ag1 = ab + (size_t)(n0 + (fb >> 2)) * HD + (fb & 3) * 8;
  unsigned short* As0 = As + w * 512;
  unsigned short* As1 = As + (4 + w) * 512;
  unsigned short* Bs0 = Bs + w * 512;
  unsigned short* Bs1 = Bs + (4 + w) * 512;

  f32x4 acc[4][4];
#pragma unroll
  for (int i = 0; i < 4; ++i)
#pragma unroll
    for (int j = 0; j < 4; ++j) acc[i][j] = (f32x4)0.f;

  for (int kt = 0; kt < HD / 32; ++kt) {
    const int ko = kt * 32;
    gload_lds16(qg0 + ko, As0);
    gload_lds16(qg1 + ko, As1);
    gload_lds16(ag0 + ko, Bs0);
    gload_lds16(ag1 + ko, Bs1);
    __syncthreads();
    s16x8 af[4], bfr[4];
#pragma unroll
    for (int i = 0; i < 4; ++i) {
      af[i]  = *(const s16x8*)&As[(moff + i * 16 + lrow) * 32 + quad * 8];
      bfr[i] = *(const s16x8*)&Bs[(noff + i * 16 + lrow) * 32 + quad * 8];
    }
#pragma unroll
    for (int i = 0; i < 4; ++i)
#pragma unroll
      for (int j = 0; j < 4; ++j)
        acc[i][j] = __builtin_amdgcn_mfma_f32_16x16x32_bf16(af[i], bfr[j], acc[i][j], 0, 0, 0);
    __syncthreads();
  }

  // --- epilogue: mask/exp in-place, stats via shfl+atomics, E/ET via LDS ---
  const float temp = temp_p[0];
  const int* qmb = qmask + b * LQA;
  const int* amb = amask + b * LQA;
  float amv[4], qmv[4][4];
#pragma unroll
  for (int j = 0; j < 4; ++j)
    amv[j] = (amb[n0 + noff + j * 16 + lrow] != 0) ? 1.f : 0.f;
#pragma unroll
  for (int i = 0; i < 4; ++i)
#pragma unroll
    for (int r = 0; r < 4; ++r)
      qmv[i][r] = (qmb[m0 + moff + i * 16 + quad * 4 + r] != 0) ? 1.f : 0.f;

#pragma unroll
  for (int i = 0; i < 4; ++i)
#pragma unroll
    for (int j = 0; j < 4; ++j)
#pragma unroll
      for (int r = 0; r < 4; ++r)
        acc[i][j][r] = __expf(acc[i][j][r] * temp) * amv[j] * qmv[i][r];

  // row sums (over a): each lane sums its 4 j, reduce over 16 lrow lanes
#pragma unroll
  for (int i = 0; i < 4; ++i)
#pragma unroll
    for (int r = 0; r < 4; ++r) {
      float rs = acc[i][0][r] + acc[i][1][r] + acc[i][2][r] + acc[i][3][r];
      rs += __shfl_xor(rs, 1);
      rs += __shfl_xor(rs, 2);
      rs += __shfl_xor(rs, 4);
      rs += __shfl_xor(rs, 8);
      if (lrow == 0)
        atomicAdd(&sumEq[b * LQA + m0 + moff + i * 16 + quad * 4 + r], rs);
    }
  // col sums (over q): sum over i,r then reduce over quads
#pragma unroll
  for (int j = 0; j < 4; ++j) {
    float cs = 0.f;
#pragma unroll
    for (int i = 0; i < 4; ++i)
#pragma unroll
      for (int r = 0; r < 4; ++r) cs += acc[i][j][r];
    cs += __shfl_xor(cs, 16);
    cs += __shfl_xor(cs, 32);
    if (quad == 0)
      atomicAdd(&sumEa[b * LQA + n0 + noff + j * 16 + lrow], cs);
  }

  // E / ET writes in two column-phases; active waves own the phase's 64 cols
  const size_t Ebase = (size_t)b * LQA * LQA;
#pragma unroll
  for (int ph = 0; ph < 2; ++ph) {
    if ((w >> 1) == ph) {
#pragma unroll
      for (int i = 0; i < 4; ++i)
#pragma unroll
        for (int j = 0; j < 4; ++j) {
          int ncl = j * 16 + lrow;          // phase-local col 0..63
#pragma unroll
          for (int r = 0; r < 4; ++r) {
            int mrow = moff + i * 16 + quad * 4 + r;
            unsigned short bv = f2bf(acc[i][j][r]);
            Cs_h[mrow * 68 + ncl] = bv;
            CsT_h[ncl * 132 + mrow] = bv;
          }
        }
    }
    __syncthreads();
    // E half: 128 rows x 64 cols, vector row reads
#pragma unroll
    for (int jj = 0; jj < 8; ++jj) {
      int f = t + 256 * jj;
      int row = f >> 4;                 // 0..127
      int cl = (f & 15) * 4;            // 0..60
      u16x4 v = *(const u16x4*)&Cs_h[row * 68 + cl];
      *(u16x4*)&E[Ebase + (size_t)(m0 + row) * LQA + n0 + 64 * ph + cl] = v;
    }
    // ET half: 64 rows x 128 cols, vector row reads
#pragma unroll
    for (int jj = 0; jj < 8; ++jj) {
      int f = t + 256 * jj;
      int row = f >> 5;                 // 0..63
      int cl = (f & 31) * 4;            // 0..124
      u16x4 v = *(const u16x4*)&CsT_h[row * 132 + cl];
      *(u16x4*)&ET[Ebase + (size_t)(n0 + 64 * ph + row) * LQA + m0 + cl] = v;
    }
    __syncthreads();
  }
}

// ---------------------------------------------------------------------------
// K3: aggregation GEMM.
//   out[b,m,512+n] = inv(s[m]) * sum_k Emat[m,k]*Bt[n,k] + add(s[m]) * bsum[n]
// where s = raw row sums; inv = 1/s if s>0 else 0; add = 0 if s>0 else 1/1024.
// grid: (8 mt, 4 nt, NB), block 256
// ---------------------------------------------------------------------------
__global__ __launch_bounds__(256) void k_agg(
    const unsigned short* __restrict__ Emat,
    const unsigned short* __restrict__ Bt,
    const float* __restrict__ rowsum,
    const float* __restrict__ bsum,
    float* __restrict__ outp)
{
  const int b  = blockIdx.z;
  const int m0 = blockIdx.x * 128;
  const int n0 = blockIdx.y * 128;
  const int t  = threadIdx.x;
  const int lane = t & 63;
  const int w  = t >> 6;
  const int moff = (w & 1) * 64;
  const int noff = (w >> 1) * 64;
  const int lrow = lane & 15;
  const int quad = lane >> 4;

  __shared__ __align__(16) unsigned short As[128 * 32];
  __shared__ __align__(16) unsigned short Bs[128 * 32];

  const unsigned short* Eb = Emat + (size_t)b * LQA * LQA;
  const unsigned short* Bb = Bt + (size_t)b * HD * LQA;

  const int fa = t, fb = t + 256;
  const unsigned short* eg0 = Eb + (size_t)(m0 + (fa >> 2)) * LQA + (fa & 3) * 8;
  const unsigned short* eg1 = Eb + (size_t)(m0 + (fb >> 2)) * LQA + (fb & 3) * 8;
  const unsigned short* bg0 = Bb + (size_t)(n0 + (fa >> 2)) * LQA + (fa & 3) * 8;
  const unsigned short* bg1 = Bb + (size_t)(n0 + (fb >> 2)) * LQA + (fb & 3) * 8;
  unsigned short* As0 = As + w * 512;
  unsigned short* As1 = As + (4 + w) * 512;
  unsigned short* Bs0 = Bs + w * 512;
  unsigned short* Bs1 = Bs + (4 + w) * 512;

  f32x4 acc[4][4];
#pragma unroll
  for (int i = 0; i < 4; ++i)
#pragma unroll
    for (int j = 0; j < 4; ++j) acc[i][j] = (f32x4)0.f;

  for (int kt = 0; kt < LQA / 32; ++kt) {
    const int ko = kt * 32;
    gload_lds16(eg0 + ko, As0);
    gload_lds16(eg1 + ko, As1);
    gload_lds16(bg0 + ko, Bs0);
    gload_lds16(bg1 + ko, Bs1);
    __syncthreads();
    s16x8 af[4], bfr[4];
#pragma unroll
    for (int i = 0; i < 4; ++i) {
      af[i]  = *(const s16x8*)&As[(moff + i * 16 + lrow) * 32 + quad * 8];
      bfr[i] = *(const s16x8*)&Bs[(noff + i * 16 + lrow) * 32 + quad * 8];
    }
#pragma unroll
    for (int i = 0; i < 4; ++i)
#pragma unroll
      for (int j = 0; j < 4; ++j)
        acc[i][j] = __builtin_amdgcn_mfma_f32_16x16x32_bf16(af[i], bfr[j], acc[i][j], 0, 0, 0);
    __syncthreads();
  }

  const float* rs = rowsum + b * LQA;
  const float* bs = bsum + b * HD;
  float* ob = outp + (size_t)b * LQA * 1024;
#pragma unroll
  for (int i = 0; i < 4; ++i) {
#pragma unroll
    for (int j = 0; j < 4; ++j) {
      int ncol = noff + j * 16 + lrow;
      float bsv = bs[n0 + ncol];
#pragma unroll
      for (int r = 0; r < 4; ++r) {
        int mrow = moff + i * 16 + quad * 4 + r;
        float s = rs[m0 + mrow];
        float inv = (s > 0.f) ? (1.f / s) : 0.f;
        float add = (s > 0.f) ? 0.f : (1.f / 1024.f);
        ob[(size_t)(m0 + mrow) * 1024 + 512 + n0 + ncol] =
            inv * acc[i][j][r] + add * bsv;
      }
    }
  }
}

// ---------------------------------------------------------------------------
extern "C" void kernel_launch(void* const* d_in, const int* in_sizes, int n_in,
                              void* d_out, int out_size, void* d_ws, size_t ws_size,
                              hipStream_t stream) {
  (void)in_sizes; (void)n_in; (void)out_size; (void)ws_size;
  const float* q    = (const float*)d_in[0];
  const float* a    = (const float*)d_in[1];
  const int*   qm   = (const int*)d_in[2];
  const int*   am   = (const int*)d_in[3];
  const float* temp = (const float*)d_in[4];

  float* out0 = (float*)d_out;                         // [NB][LQA][1024] concat(q, q_s)
  float* out1 = out0 + (size_t)NB * LQA * 1024;        // [NB][LQA][1024] concat(a, a_s)

  char* ws = (char*)d_ws;
  const size_t MB = 1024ull * 1024ull;
  unsigned short* E    = (unsigned short*)(ws);                 //  64 MB
  unsigned short* ET   = (unsigned short*)(ws + 64 * MB);       //  64 MB
  unsigned short* qT   = (unsigned short*)(ws + 128 * MB);      //  32 MB
  unsigned short* aT   = (unsigned short*)(ws + 160 * MB);      //  32 MB
  unsigned short* qb16 = (unsigned short*)(ws + 192 * MB);      //  32 MB
  unsigned short* ab16 = (unsigned short*)(ws + 224 * MB);      //  32 MB
  char* stats = ws + 256 * MB;
  float* sumEq = (float*)(stats);                 // 128 KB  [NB][LQA]
  float* sumEa = (float*)(stats + 131072);        // 128 KB  [NB][LQA]
  float* qsum  = (float*)(stats + 262144);        //  64 KB  [NB][HD]
  float* asum  = (float*)(stats + 327680);        //  64 KB  [NB][HD]
  // zero all atomic accumulators (ws is poisoned 0xAA before every call)
  hipMemsetAsync(stats, 0, 393216, stream);

  k_prep<<<dim3(8, 16, 2 * NB), 256, 0, stream>>>(q, a, out0, out1, qT, aT,
                                                  qb16, ab16, qsum, asum);
  k_scores<<<dim3(8, 8, NB), 256, 0, stream>>>(qb16, ab16, qm, am, temp,
                                               E, ET, sumEq, sumEa);
  k_agg<<<dim3(8, 4, NB), 256, 0, stream>>>(E,  aT, sumEq, asum, out0);  // q_s
  k_agg<<<dim3(8, 4, NB), 256, 0, stream>>>(ET, qT, sumEa, qsum, out1);  // a_s
}